// Round 2
// baseline (251.502 us; speedup 1.0000x reference)
//
#include <hip/hip_runtime.h>
#include <hip/hip_bf16.h>

// SelfAttention: N=8192, D_IN=512, D_K=64, fp32 in/out.
// R1 scheme:
//   K0a split_x : X fp32 -> xh/xl bf16 (memory-bound, vectorized, no elementwise vector writes)
//   K0b prep_w  : W fp32 -> wh/wl bf16 [192][512]
//   K1  qkv2    : 3072 one-wave blocks (12 blocks/CU). Each wave: 16 rows x 32 cols, K=512,
//                 split-bf16 (hh+hl+lh). Outputs q/k hi+lo [8192x64] and Vt [64x8192] bf16.
//   K2  attn2   : grid 512 = (256 q-tiles x 2 key-halves), 8 waves, 32 q/block, 512 keys/wave.
//                 __launch_bounds__(512,4) -> 2 blocks/CU (4 waves/SIMD).
//                 QK^T split-bf16 (6 MFMA / 16x16 pair), defer-max THR=8, row-sum via
//                 MFMA-with-ones (no sum shuffles), P through padded LDS, PV bf16,
//                 in-block LDS merge of 8 wave partials -> fp32 (num,den,M) per key-half to ws.
//   K3  merge2  : combine the 2 key-half partials -> out.
// Numerics: score err ~0.02 (split-bf16) vs ~0.3 budget; defer-max is reference-shift exact.

#define N_TOK 8192
#define D_INN 512
#define DK    64

typedef __attribute__((ext_vector_type(8))) short bf16x8;
typedef __attribute__((ext_vector_type(4))) float f32x4;

__device__ __forceinline__ unsigned f2bf_u(float f) {
  union { float f; unsigned u; } v; v.f = f;
  return (v.u + 0x7FFFu + ((v.u >> 16) & 1u)) >> 16;
}
__device__ __forceinline__ unsigned short f2bf(float f) { return (unsigned short)f2bf_u(f); }
__device__ __forceinline__ float bf2f(unsigned short h) {
  union { unsigned u; float f; } v; v.u = ((unsigned)h) << 16; return v.f;
}
__device__ __forceinline__ unsigned packbf(float a, float b) {
  return f2bf_u(a) | (f2bf_u(b) << 16);
}
__device__ __forceinline__ void split2(float a, float b, unsigned& hi, unsigned& lo) {
  unsigned ha = f2bf_u(a), hb = f2bf_u(b);
  float ra = a - bf2f((unsigned short)ha);
  float rb = b - bf2f((unsigned short)hb);
  hi = ha | (hb << 16);
  lo = f2bf_u(ra) | (f2bf_u(rb) << 16);
}

// ---------------- K0a: split X into bf16 hi/lo (pure bit-op packing, no arrays) ----------
__global__ __launch_bounds__(256) void split_x(const float* __restrict__ X,
                                               unsigned* __restrict__ xh,
                                               unsigned* __restrict__ xl) {
  int i = blockIdx.x * 256 + threadIdx.x;  // handles floats [8i, 8i+8)
  const float4 a = *(const float4*)(X + i * 8);
  const float4 b = *(const float4*)(X + i * 8 + 4);
  uint4 H, L;
  split2(a.x, a.y, H.x, L.x);
  split2(a.z, a.w, H.y, L.y);
  split2(b.x, b.y, H.z, L.z);
  split2(b.z, b.w, H.w, L.w);
  *(uint4*)(xh + i * 4) = H;
  *(uint4*)(xl + i * 4) = L;
}

// ---------------- K0b: split W into bf16 hi/lo ----------------
__global__ __launch_bounds__(256) void prep_w(
    const float* __restrict__ Wq, const float* __restrict__ Wk, const float* __restrict__ Wv,
    unsigned short* __restrict__ w_hi, unsigned short* __restrict__ w_lo) {
  int t = blockIdx.x * 256 + threadIdx.x;
  if (t >= 192 * 512) return;
  const float* src = (t < 64 * 512) ? Wq : ((t < 128 * 512) ? Wk : Wv);
  float x = src[t & (64 * 512 - 1)];
  unsigned short h = f2bf(x);
  w_hi[t] = h;
  w_lo[t] = f2bf(x - bf2f(h));
}

// ---------------- K1: QKV projection ----------------
// grid 3072 = 512 row-tiles x 6 col-segments (each 32 cols of the 192 = q|k|v x 64).
__global__ __launch_bounds__(64) void qkv2(
    const unsigned short* __restrict__ xh, const unsigned short* __restrict__ xl,
    const unsigned short* __restrict__ wh, const unsigned short* __restrict__ wl,
    unsigned short* __restrict__ q_hi, unsigned short* __restrict__ q_lo,
    unsigned short* __restrict__ k_hi, unsigned short* __restrict__ k_lo,
    unsigned short* __restrict__ vt) {
  const int l = threadIdx.x, l15 = l & 15, g = l >> 4;
  const int b = blockIdx.x;
  const int rt = b / 6, seg = b % 6;
  const int row0 = rt * 16;

  f32x4 acc[2] = {f32x4{0.f, 0.f, 0.f, 0.f}, f32x4{0.f, 0.f, 0.f, 0.f}};

  for (int kc = 0; kc < D_INN; kc += 32) {
    const int xoff = (row0 + l15) * D_INN + kc + g * 8;
    bf16x8 ah = *(const bf16x8*)(xh + xoff);
    bf16x8 al = *(const bf16x8*)(xl + xoff);
#pragma unroll
    for (int s = 0; s < 2; s++) {
      const int woff = (seg * 32 + s * 16 + l15) * D_INN + kc + g * 8;
      bf16x8 bh = *(const bf16x8*)(wh + woff);
      bf16x8 bl = *(const bf16x8*)(wl + woff);
      acc[s] = __builtin_amdgcn_mfma_f32_16x16x32_bf16(ah, bh, acc[s], 0, 0, 0);
      acc[s] = __builtin_amdgcn_mfma_f32_16x16x32_bf16(ah, bl, acc[s], 0, 0, 0);
      acc[s] = __builtin_amdgcn_mfma_f32_16x16x32_bf16(al, bh, acc[s], 0, 0, 0);
    }
  }

  if (seg < 4) {
    unsigned short* hi = (seg < 2) ? q_hi : k_hi;
    unsigned short* lo = (seg < 2) ? q_lo : k_lo;
    const int colbase = (seg & 1) * 32;
#pragma unroll
    for (int s = 0; s < 2; s++) {
      const int col = colbase + s * 16 + l15;
#pragma unroll
      for (int r = 0; r < 4; r++) {
        const int row = row0 + g * 4 + r;
        float v = acc[s][r];
        unsigned short h = f2bf(v);
        hi[row * DK + col] = h;
        lo[row * DK + col] = f2bf(v - bf2f(h));
      }
    }
  } else {
#pragma unroll
    for (int s = 0; s < 2; s++) {
      const int d = (seg - 4) * 32 + s * 16 + l15;
      uint2 pk;
      pk.x = packbf(acc[s][0], acc[s][1]);
      pk.y = packbf(acc[s][2], acc[s][3]);
      *(uint2*)(vt + d * N_TOK + row0 + g * 4) = pk;
    }
  }
}

// ---------------- K2: flash attention over one key-half ----------------
// grid 512 = (q-tile qt = bid>>1) x (key-half = bid&1); 8 waves; wave handles 512 keys.
__global__ __launch_bounds__(512, 4) void attn2(
    const unsigned short* __restrict__ q_hi, const unsigned short* __restrict__ q_lo,
    const unsigned short* __restrict__ k_hi, const unsigned short* __restrict__ k_lo,
    const unsigned short* __restrict__ vt,
    float* __restrict__ pnum, float* __restrict__ pden, float* __restrict__ pM) {
  extern __shared__ char smem[];
  unsigned short* P_lds = (unsigned short*)smem;            // [8][16][72]
  unsigned short* OmS   = (unsigned short*)(smem + 18432);  // [8][32][64]
  float* Mw = (float*)(smem + 18432 + 32768);               // [8][32]
  float* Lw = Mw + 256;                                     // [8][32]

  const int tid = threadIdx.x;
  const int l = tid & 63, wid = tid >> 6;
  const int l15 = l & 15, g = l >> 4;
  const int qt = blockIdx.x >> 1, half = blockIdx.x & 1;
  const int qb = qt * 32;

  bf16x8 qhf[2][2], qlf[2][2];
#pragma unroll
  for (int u = 0; u < 2; u++)
#pragma unroll
    for (int c = 0; c < 2; c++) {
      int row = qb + u * 16 + l15;
      qhf[u][c] = *(const bf16x8*)(q_hi + row * DK + c * 32 + g * 8);
      qlf[u][c] = *(const bf16x8*)(q_lo + row * DK + c * 32 + g * 8);
    }

  const short onec = (short)0x3F80;
  const bf16x8 ones = {onec, onec, onec, onec, onec, onec, onec, onec};

  float m[2][4];
  f32x4 accO[2][4], accL[2];
#pragma unroll
  for (int u = 0; u < 2; u++) {
    accL[u] = f32x4{0.f, 0.f, 0.f, 0.f};
#pragma unroll
    for (int r = 0; r < 4; r++) m[u][r] = -1e30f;
#pragma unroll
    for (int ds = 0; ds < 4; ds++) accO[u][ds] = f32x4{0.f, 0.f, 0.f, 0.f};
  }

  const int k0 = half * (N_TOK / 2) + wid * 512;
  for (int kt = k0; kt < k0 + 512; kt += 64) {
    // ---- S = Q K^T / 8 (4 key-subtiles x 2 q-subtiles, split-bf16) ----
    float st[2][4][4];
#pragma unroll
    for (int s = 0; s < 4; s++) {
      bf16x8 khf[2], klf[2];
#pragma unroll
      for (int c = 0; c < 2; c++) {
        int krow = kt + s * 16 + l15;
        khf[c] = *(const bf16x8*)(k_hi + krow * DK + c * 32 + g * 8);
        klf[c] = *(const bf16x8*)(k_lo + krow * DK + c * 32 + g * 8);
      }
      __builtin_amdgcn_s_setprio(1);
#pragma unroll
      for (int u = 0; u < 2; u++) {
        f32x4 sa = f32x4{0.f, 0.f, 0.f, 0.f};
        sa = __builtin_amdgcn_mfma_f32_16x16x32_bf16(qhf[u][0], khf[0], sa, 0, 0, 0);
        sa = __builtin_amdgcn_mfma_f32_16x16x32_bf16(qhf[u][1], khf[1], sa, 0, 0, 0);
        sa = __builtin_amdgcn_mfma_f32_16x16x32_bf16(qhf[u][0], klf[0], sa, 0, 0, 0);
        sa = __builtin_amdgcn_mfma_f32_16x16x32_bf16(qhf[u][1], klf[1], sa, 0, 0, 0);
        sa = __builtin_amdgcn_mfma_f32_16x16x32_bf16(qlf[u][0], khf[0], sa, 0, 0, 0);
        sa = __builtin_amdgcn_mfma_f32_16x16x32_bf16(qlf[u][1], khf[1], sa, 0, 0, 0);
#pragma unroll
        for (int r = 0; r < 4; r++) st[u][s][r] = sa[r] * 0.125f;
      }
      __builtin_amdgcn_s_setprio(0);
    }

    // ---- online softmax (defer-max THR=8), P->LDS, l via MFMA-with-ones ----
    bf16x8 pa[2][2];
#pragma unroll
    for (int u = 0; u < 2; u++) {
      float tmax[4];
#pragma unroll
      for (int r = 0; r < 4; r++) {
        float t = fmaxf(fmaxf(st[u][0][r], st[u][1][r]), fmaxf(st[u][2][r], st[u][3][r]));
#pragma unroll
        for (int off = 1; off < 16; off <<= 1) t = fmaxf(t, __shfl_xor(t, off, 64));
        tmax[r] = t;
      }
      bool grow = (tmax[0] > m[u][0] + 8.f) || (tmax[1] > m[u][1] + 8.f) ||
                  (tmax[2] > m[u][2] + 8.f) || (tmax[3] > m[u][3] + 8.f);
      if (__any(grow)) {
#pragma unroll
        for (int r = 0; r < 4; r++) {
          float mn = fmaxf(m[u][r], tmax[r]);
          float fac = __expf(m[u][r] - mn);
          m[u][r] = mn;
          accL[u][r] *= fac;
#pragma unroll
          for (int ds = 0; ds < 4; ds++) accO[u][ds][r] *= fac;
        }
      }
#pragma unroll
      for (int s = 0; s < 4; s++)
#pragma unroll
        for (int r = 0; r < 4; r++) {
          float p = __expf(st[u][s][r] - m[u][r]);
          P_lds[(wid * 16 + g * 4 + r) * 72 + s * 16 + l15] = f2bf(p);
        }
#pragma unroll
      for (int c = 0; c < 2; c++)
        pa[u][c] = *(const bf16x8*)&P_lds[(wid * 16 + l15) * 72 + c * 32 + g * 8];
      accL[u] = __builtin_amdgcn_mfma_f32_16x16x32_bf16(pa[u][0], ones, accL[u], 0, 0, 0);
      accL[u] = __builtin_amdgcn_mfma_f32_16x16x32_bf16(pa[u][1], ones, accL[u], 0, 0, 0);
    }

    // ---- PV ----
#pragma unroll
    for (int ds = 0; ds < 4; ds++) {
      bf16x8 vb[2];
#pragma unroll
      for (int c = 0; c < 2; c++)
        vb[c] = *(const bf16x8*)(vt + (ds * 16 + l15) * N_TOK + kt + c * 32 + g * 8);
      __builtin_amdgcn_s_setprio(1);
#pragma unroll
      for (int u = 0; u < 2; u++) {
        accO[u][ds] = __builtin_amdgcn_mfma_f32_16x16x32_bf16(pa[u][0], vb[0], accO[u][ds], 0, 0, 0);
        accO[u][ds] = __builtin_amdgcn_mfma_f32_16x16x32_bf16(pa[u][1], vb[1], accO[u][ds], 0, 0, 0);
      }
      __builtin_amdgcn_s_setprio(0);
    }
  }

  // ---- per-wave partials -> LDS ----
#pragma unroll
  for (int u = 0; u < 2; u++) {
#pragma unroll
    for (int ds = 0; ds < 4; ds++)
#pragma unroll
      for (int r = 0; r < 4; r++)
        OmS[(wid * 32 + u * 16 + g * 4 + r) * 64 + ds * 16 + l15] = f2bf(accO[u][ds][r]);
    if (l15 == 0) {
#pragma unroll
      for (int r = 0; r < 4; r++) {
        Mw[wid * 32 + u * 16 + g * 4 + r] = m[u][r];
        Lw[wid * 32 + u * 16 + g * 4 + r] = accL[u][r];
      }
    }
  }
  __syncthreads();

  // ---- block merge of 8 wave partials -> fp32 (num, den, M) for this key-half ----
  for (int i = tid; i < 32 * 64; i += 512) {
    int q = i >> 6, d = i & 63;
    float M = -1e30f;
#pragma unroll
    for (int w = 0; w < 8; w++) M = fmaxf(M, Mw[w * 32 + q]);
    float num = 0.f, den = 0.f;
#pragma unroll
    for (int w = 0; w < 8; w++) {
      float e = __expf(Mw[w * 32 + q] - M);
      num += bf2f(OmS[(w * 32 + q) * 64 + d]) * e;
      den += Lw[w * 32 + q] * e;
    }
    int qg = qb + q;
    pnum[(half * N_TOK + qg) * DK + d] = num;
    if (d == 0) {
      pden[half * N_TOK + qg] = den;
      pM[half * N_TOK + qg] = M;
    }
  }
}

// ---------------- K3: merge the two key-half partials ----------------
__global__ __launch_bounds__(256) void merge2(
    const float* __restrict__ pnum, const float* __restrict__ pden,
    const float* __restrict__ pM, float* __restrict__ out) {
  int i = blockIdx.x * 256 + threadIdx.x;
  int q = i >> 6, d = i & 63;
  float m0 = pM[q], m1 = pM[N_TOK + q];
  float M = fmaxf(m0, m1);
  float e0 = __expf(m0 - M), e1 = __expf(m1 - M);
  float n = pnum[q * DK + d] * e0 + pnum[(N_TOK + q) * DK + d] * e1;
  float dn = pden[q] * e0 + pden[N_TOK + q] * e1;
  out[i] = n / dn;
}

// ---------------- host launch ----------------
extern "C" void kernel_launch(void* const* d_in, const int* in_sizes, int n_in,
                              void* d_out, int out_size, void* d_ws, size_t ws_size,
                              hipStream_t stream) {
  (void)in_sizes; (void)n_in; (void)out_size; (void)ws_size;
  const float* X  = (const float*)d_in[0];
  const float* Wq = (const float*)d_in[1];
  const float* Wk = (const float*)d_in[2];
  const float* Wv = (const float*)d_in[3];

  unsigned short* base = (unsigned short*)d_ws;
  unsigned short* xh = base;                          // 8192*512
  unsigned short* xl = xh + N_TOK * D_INN;            // 8192*512
  unsigned short* qh = xl + N_TOK * D_INN;            // 8192*64
  unsigned short* ql = qh + N_TOK * DK;
  unsigned short* kh = ql + N_TOK * DK;
  unsigned short* kl = kh + N_TOK * DK;
  unsigned short* vt = kl + N_TOK * DK;               // 64*8192
  unsigned short* wh = vt + DK * N_TOK;               // 192*512
  unsigned short* wl = wh + 192 * D_INN;
  // partials alias the x-split region (dead after qkv2): 4.25 MB < 16 MB
  float* pnum = (float*)d_ws;                         // [2][8192][64]
  float* pden = pnum + 2 * N_TOK * DK;                // [2][8192]
  float* pM   = pden + 2 * N_TOK;                     // [2][8192]

  split_x<<<(N_TOK * D_INN) / (256 * 8), 256, 0, stream>>>(X, (unsigned*)xh, (unsigned*)xl);
  prep_w<<<384, 256, 0, stream>>>(Wq, Wk, Wv, wh, wl);
  qkv2<<<(N_TOK / 16) * 6, 64, 0, stream>>>(xh, xl, wh, wl, qh, ql, kh, kl, vt);
  attn2<<<512, 512, 18432 + 32768 + 2048, stream>>>(qh, ql, kh, kl, vt, pnum, pden, pM);
  merge2<<<(N_TOK * DK) / 256, 256, 0, stream>>>(pnum, pden, pM, (float*)d_out);
}

// Round 4
// 153.526 us; speedup vs baseline: 1.6382x; 1.6382x over previous
//
#include <hip/hip_runtime.h>
#include <hip/hip_bf16.h>

// SelfAttention N=8192, D_IN=512, D_K=64 (fp32 io).
// R3 = R2 with the (provably broken) shuffle P-redistribute replaced by the
// R1-proven per-wave LDS transpose. Everything else unchanged:
//   split_x: X fp32 -> xh/xl bf16
//   prep_w : W fp32 -> wh/wl bf16 [192][512]
//   qkv2   : 512 blocks x 256thr; Q scaled 1/8 split hi/lo row-major;
//            K split hi/lo in K'-frag order; V bf16 in V'-frag order.
//   attn3  : grid 512 = 64 qblocks x 8 key-splits; 4 waves; wave: 32 q x 1024 keys.
//            Swapped QK^T (scores lane-local, q = lane&15), defer-max THR=8,
//            P -> per-wave LDS tile (stride 72) -> b128 A-frags, rowsum via
//            MFMA-with-ones on truncated P, PV bf16.
//   merge8 : combine 8 key-split partials.

#define N_TOK 8192
#define D_INN 512
#define DK    64

typedef __attribute__((ext_vector_type(8))) short bf16x8;
typedef __attribute__((ext_vector_type(4))) float f32x4;

static __device__ __forceinline__ unsigned f2bf_u(float f) {
  union { float f; unsigned u; } v; v.f = f;
  return (v.u + 0x7FFFu + ((v.u >> 16) & 1u)) >> 16;
}
static __device__ __forceinline__ unsigned short f2bf(float f) { return (unsigned short)f2bf_u(f); }
static __device__ __forceinline__ float bf2f(unsigned short h) {
  union { unsigned u; float f; } v; v.u = ((unsigned)h) << 16; return v.f;
}
static __device__ __forceinline__ unsigned truncpk(float a, float b) {
  union { float f; unsigned u; } x, y; x.f = a; y.f = b;
  return (x.u >> 16) | (y.u & 0xFFFF0000u);
}
static __device__ __forceinline__ void split2(float a, float b, unsigned& hi, unsigned& lo) {
  unsigned ha = f2bf_u(a), hb = f2bf_u(b);
  float ra = a - bf2f((unsigned short)ha);
  float rb = b - bf2f((unsigned short)hb);
  hi = ha | (hb << 16);
  lo = f2bf_u(ra) | (f2bf_u(rb) << 16);
}

// ---------------- split X ----------------
__global__ __launch_bounds__(256) void split_x(const float* __restrict__ X,
                                               unsigned* __restrict__ xh,
                                               unsigned* __restrict__ xl) {
  int i = blockIdx.x * 256 + threadIdx.x;
  const float4 a = *(const float4*)(X + i * 8);
  const float4 b = *(const float4*)(X + i * 8 + 4);
  uint4 H, L;
  split2(a.x, a.y, H.x, L.x);
  split2(a.z, a.w, H.y, L.y);
  split2(b.x, b.y, H.z, L.z);
  split2(b.z, b.w, H.w, L.w);
  *(uint4*)(xh + i * 4) = H;
  *(uint4*)(xl + i * 4) = L;
}

// ---------------- split W ----------------
__global__ __launch_bounds__(256) void prep_w(
    const float* __restrict__ Wq, const float* __restrict__ Wk, const float* __restrict__ Wv,
    unsigned short* __restrict__ wh, unsigned short* __restrict__ wl) {
  int t = blockIdx.x * 256 + threadIdx.x;
  if (t >= 192 * 512) return;
  const float* src = (t < 64 * 512) ? Wq : ((t < 128 * 512) ? Wk : Wv);
  float x = src[t & (64 * 512 - 1)];
  unsigned short h = f2bf(x);
  wh[t] = h;
  wl[t] = f2bf(x - bf2f(h));
}

// ---------------- QKV projection ----------------
// grid 512 (16 tokens each) x 256 thr. Wave w handles col-tiles {w(Q), w(K), w(V)}.
__global__ __launch_bounds__(256, 2) void qkv2(
    const unsigned short* __restrict__ xh, const unsigned short* __restrict__ xl,
    const unsigned short* __restrict__ wh, const unsigned short* __restrict__ wl,
    unsigned short* __restrict__ qhp, unsigned short* __restrict__ qlp,
    unsigned short* __restrict__ kph, unsigned short* __restrict__ kpl,
    unsigned short* __restrict__ vp) {
  const int tid = threadIdx.x, w = tid >> 6, l = tid & 63;
  const int l15 = l & 15, g = l >> 4;
  const int t0 = blockIdx.x * 16;
  const int dq = w * 16;  // output-dim base within 64

  f32x4 aq = {0.f, 0.f, 0.f, 0.f}, ak = aq, av = aq;

  for (int kc = 0; kc < D_INN; kc += 32) {
    const int xoff = (t0 + l15) * D_INN + kc + g * 8;
    bf16x8 ah = *(const bf16x8*)(xh + xoff);
    bf16x8 al = *(const bf16x8*)(xl + xoff);
    const int wq_off = (dq + l15) * D_INN + kc + g * 8;
    const int wk_off = (64 + dq + l15) * D_INN + kc + g * 8;
    const int wv_off = (128 + dq + l15) * D_INN + kc + g * 8;
    bf16x8 bqh = *(const bf16x8*)(wh + wq_off);
    bf16x8 bql = *(const bf16x8*)(wl + wq_off);
    bf16x8 bkh = *(const bf16x8*)(wh + wk_off);
    bf16x8 bkl = *(const bf16x8*)(wl + wk_off);
    bf16x8 bvh = *(const bf16x8*)(wh + wv_off);
    aq = __builtin_amdgcn_mfma_f32_16x16x32_bf16(ah, bqh, aq, 0, 0, 0);
    aq = __builtin_amdgcn_mfma_f32_16x16x32_bf16(ah, bql, aq, 0, 0, 0);
    aq = __builtin_amdgcn_mfma_f32_16x16x32_bf16(al, bqh, aq, 0, 0, 0);
    ak = __builtin_amdgcn_mfma_f32_16x16x32_bf16(ah, bkh, ak, 0, 0, 0);
    ak = __builtin_amdgcn_mfma_f32_16x16x32_bf16(ah, bkl, ak, 0, 0, 0);
    ak = __builtin_amdgcn_mfma_f32_16x16x32_bf16(al, bkh, ak, 0, 0, 0);
    av = __builtin_amdgcn_mfma_f32_16x16x32_bf16(ah, bvh, av, 0, 0, 0);
    av = __builtin_amdgcn_mfma_f32_16x16x32_bf16(al, bvh, av, 0, 0, 0);
  }

  // Q: fold 1/8 scale, split hi/lo, row-major [8192][64]
#pragma unroll
  for (int r = 0; r < 4; r++) {
    float v = aq[r] * 0.125f;
    int row = t0 + g * 4 + r;
    unsigned short h = f2bf(v);
    qhp[row * DK + dq + l15] = h;
    qlp[row * DK + dq + l15] = f2bf(v - bf2f(h));
  }
  // K: split hi/lo, K'-frag order
#pragma unroll
  for (int r = 0; r < 4; r++) {
    float v = ak[r];
    int t = t0 + g * 4 + r;
    int d = dq + l15;
    int off = (t >> 5) * 2048 + ((t >> 4) & 1) * 1024 + (d >> 5) * 512 +
              ((t & 15) + (((d >> 3) & 3) << 4)) * 8 + (d & 7);
    unsigned short h = f2bf(v);
    kph[off] = h;
    kpl[off] = f2bf(v - bf2f(h));
  }
  // V: single bf16, V'-frag order, 4 consecutive tokens packed (8B)
  {
    int tg = t0 + g * 4;
    int d = dq + l15;
    int off = (tg >> 5) * 2048 + (d >> 4) * 512 +
              (((d & 15) + (((tg >> 3) & 3) << 4))) * 8 + (tg & 7);
    uint2 pk;
    pk.x = f2bf_u(av[0]) | (f2bf_u(av[1]) << 16);
    pk.y = f2bf_u(av[2]) | (f2bf_u(av[3]) << 16);
    *(uint2*)(vp + off) = pk;
  }
}

// ---------------- flash attention ----------------
// grid 512 = 64 qblocks x 8 key-splits; 256 thr (4 waves); wave: 32 q-rows x 1024 keys.
__global__ __launch_bounds__(256, 2) void attn3(
    const unsigned short* __restrict__ qhp, const unsigned short* __restrict__ qlp,
    const unsigned short* __restrict__ kph, const unsigned short* __restrict__ kpl,
    const unsigned short* __restrict__ vp,
    float* __restrict__ pnum, float* __restrict__ pden, float* __restrict__ pM) {
  // per-wave, per-u P staging tile: [4 waves][2 u][16 q][72]
  __shared__ unsigned short P_lds[4 * 2 * 16 * 72];

  const int tid = threadIdx.x, w = tid >> 6, l = tid & 63;
  const int l15 = l & 15, g = l >> 4;
  const int qblk = blockIdx.x >> 3, ks = blockIdx.x & 7;
  const int wq0 = qblk * 128 + w * 32;

  // Q fragments (B-operand of swapped QK^T)
  bf16x8 qhf[2][2], qlf[2][2];
#pragma unroll
  for (int u = 0; u < 2; u++)
#pragma unroll
    for (int c = 0; c < 2; c++) {
      int row = wq0 + u * 16 + l15;
      qhf[u][c] = *(const bf16x8*)(qhp + row * DK + c * 32 + g * 8);
      qlf[u][c] = *(const bf16x8*)(qlp + row * DK + c * 32 + g * 8);
    }

  const short onec = (short)0x3F80;
  const bf16x8 ones = {onec, onec, onec, onec, onec, onec, onec, onec};

  f32x4 accO[2][4], accL[2];
  float m[2] = {-1e30f, -1e30f};
#pragma unroll
  for (int u = 0; u < 2; u++) {
    accL[u] = f32x4{0.f, 0.f, 0.f, 0.f};
#pragma unroll
    for (int ds = 0; ds < 4; ds++) accO[u][ds] = f32x4{0.f, 0.f, 0.f, 0.f};
  }

  for (int kt = ks * 1024; kt < ks * 1024 + 1024; kt += 64) {
    const int kti = kt >> 5;

    // S^T = K Q^T (scores: col = q = lane&15, row = key via (g, reg))
    f32x4 st[2][4];
#pragma unroll
    for (int s = 0; s < 4; s++) {
      bf16x8 khf[2], klf[2];
#pragma unroll
      for (int c = 0; c < 2; c++) {
        const int off = (kti + (s >> 1)) * 2048 + (s & 1) * 1024 + c * 512 + l * 8;
        khf[c] = *(const bf16x8*)(kph + off);
        klf[c] = *(const bf16x8*)(kpl + off);
      }
      __builtin_amdgcn_s_setprio(1);
#pragma unroll
      for (int u = 0; u < 2; u++) {
        f32x4 sa = {0.f, 0.f, 0.f, 0.f};
        sa = __builtin_amdgcn_mfma_f32_16x16x32_bf16(khf[0], qhf[u][0], sa, 0, 0, 0);
        sa = __builtin_amdgcn_mfma_f32_16x16x32_bf16(khf[1], qhf[u][1], sa, 0, 0, 0);
        sa = __builtin_amdgcn_mfma_f32_16x16x32_bf16(khf[0], qlf[u][0], sa, 0, 0, 0);
        sa = __builtin_amdgcn_mfma_f32_16x16x32_bf16(khf[1], qlf[u][1], sa, 0, 0, 0);
        sa = __builtin_amdgcn_mfma_f32_16x16x32_bf16(klf[0], qhf[u][0], sa, 0, 0, 0);
        sa = __builtin_amdgcn_mfma_f32_16x16x32_bf16(klf[1], qhf[u][1], sa, 0, 0, 0);
        st[u][s] = sa;
      }
      __builtin_amdgcn_s_setprio(0);
    }

    // V fragments (global, coalesced; used after softmax)
    bf16x8 vb[4][2];
#pragma unroll
    for (int ds = 0; ds < 4; ds++)
#pragma unroll
      for (int c = 0; c < 2; c++)
        vb[ds][c] = *(const bf16x8*)(vp + (kti + c) * 2048 + ds * 512 + l * 8);

    bf16x8 pa[2][2];
#pragma unroll
    for (int u = 0; u < 2; u++) {
      // row-max: in-lane fmax + 2 cross-g shuffles (q stays = lane&15)
      float t0m = fmaxf(fmaxf(st[u][0][0], st[u][0][1]), fmaxf(st[u][0][2], st[u][0][3]));
      float t1m = fmaxf(fmaxf(st[u][1][0], st[u][1][1]), fmaxf(st[u][1][2], st[u][1][3]));
      float t2m = fmaxf(fmaxf(st[u][2][0], st[u][2][1]), fmaxf(st[u][2][2], st[u][2][3]));
      float t3m = fmaxf(fmaxf(st[u][3][0], st[u][3][1]), fmaxf(st[u][3][2], st[u][3][3]));
      float tm = fmaxf(fmaxf(t0m, t1m), fmaxf(t2m, t3m));
      tm = fmaxf(tm, __shfl_xor(tm, 16, 64));
      tm = fmaxf(tm, __shfl_xor(tm, 32, 64));
      if (__any(tm > m[u] + 8.f)) {  // defer-max (THR=8)
        float mn = fmaxf(m[u], tm);
        float fac = __expf(m[u] - mn);
        m[u] = mn;
#pragma unroll
        for (int r = 0; r < 4; r++) {
          float fr = __shfl(fac, g * 4 + r, 64);
          accL[u][r] *= fr;
#pragma unroll
          for (int ds = 0; ds < 4; ds++) accO[u][ds][r] *= fr;
        }
      }
      // P = exp(S - m); lane (q=l15, g) owns keys kappa = s*16 + g*4 + r.
      // Write to per-wave LDS row q, element kappa (u32 pairs); read back b128
      // as the PV A-fragment (row = q = l15, k = g*8 + j). R1-proven transpose.
      const int base = ((w * 2 + u) * 16 + l15) * 72;
#pragma unroll
      for (int s = 0; s < 4; s++) {
        float p0 = __expf(st[u][s][0] - m[u]);
        float p1 = __expf(st[u][s][1] - m[u]);
        float p2 = __expf(st[u][s][2] - m[u]);
        float p3 = __expf(st[u][s][3] - m[u]);
        *(unsigned*)&P_lds[base + s * 16 + g * 4]     = truncpk(p0, p1);
        *(unsigned*)&P_lds[base + s * 16 + g * 4 + 2] = truncpk(p2, p3);
      }
#pragma unroll
      for (int c = 0; c < 2; c++)
        pa[u][c] = *(const bf16x8*)&P_lds[base + c * 32 + g * 8];
      // row-sum on the SAME truncated P (num/den bias cancels)
      accL[u] = __builtin_amdgcn_mfma_f32_16x16x32_bf16(pa[u][0], ones, accL[u], 0, 0, 0);
      accL[u] = __builtin_amdgcn_mfma_f32_16x16x32_bf16(pa[u][1], ones, accL[u], 0, 0, 0);
    }

    // PV
    __builtin_amdgcn_s_setprio(1);
#pragma unroll
    for (int ds = 0; ds < 4; ds++)
#pragma unroll
      for (int u = 0; u < 2; u++) {
        accO[u][ds] = __builtin_amdgcn_mfma_f32_16x16x32_bf16(pa[u][0], vb[ds][0], accO[u][ds], 0, 0, 0);
        accO[u][ds] = __builtin_amdgcn_mfma_f32_16x16x32_bf16(pa[u][1], vb[ds][1], accO[u][ds], 0, 0, 0);
      }
    __builtin_amdgcn_s_setprio(0);
  }

  // write per-(qblock, key-split) partials
#pragma unroll
  for (int u = 0; u < 2; u++) {
#pragma unroll
    for (int ds = 0; ds < 4; ds++)
#pragma unroll
      for (int r = 0; r < 4; r++)
        pnum[(size_t)ks * (N_TOK * DK) + (wq0 + u * 16 + g * 4 + r) * DK + ds * 16 + l15] =
            accO[u][ds][r];
    if (l15 == 0) {
#pragma unroll
      for (int r = 0; r < 4; r++) pden[ks * N_TOK + wq0 + u * 16 + g * 4 + r] = accL[u][r];
    }
    if (g == 0) pM[ks * N_TOK + wq0 + u * 16 + l15] = m[u];
  }
}

// ---------------- merge 8 key-split partials ----------------
__global__ __launch_bounds__(256) void merge8(
    const float* __restrict__ pnum, const float* __restrict__ pden,
    const float* __restrict__ pM, float* __restrict__ out) {
  int i = blockIdx.x * 256 + threadIdx.x;
  int q = i >> 6, d = i & 63;
  float M = -1e30f;
#pragma unroll
  for (int s = 0; s < 8; s++) M = fmaxf(M, pM[s * N_TOK + q]);
  float num = 0.f, den = 0.f;
#pragma unroll
  for (int s = 0; s < 8; s++) {
    float e = __expf(pM[s * N_TOK + q] - M);
    num += pnum[(size_t)s * (N_TOK * DK) + q * DK + d] * e;
    den += pden[s * N_TOK + q] * e;
  }
  out[i] = num / den;
}

// ---------------- host launch ----------------
extern "C" void kernel_launch(void* const* d_in, const int* in_sizes, int n_in,
                              void* d_out, int out_size, void* d_ws, size_t ws_size,
                              hipStream_t stream) {
  (void)in_sizes; (void)n_in; (void)out_size; (void)ws_size;
  const float* X  = (const float*)d_in[0];
  const float* Wq = (const float*)d_in[1];
  const float* Wk = (const float*)d_in[2];
  const float* Wv = (const float*)d_in[3];

  char* base = (char*)d_ws;
  unsigned short* xh  = (unsigned short*)(base);                  // 8 MB
  unsigned short* xl  = (unsigned short*)(base + 8388608);        // 8 MB
  unsigned short* qhp = (unsigned short*)(base + 16777216);       // 1 MB
  unsigned short* qlp = (unsigned short*)(base + 17825792);       // 1 MB
  unsigned short* kph = (unsigned short*)(base + 18874368);       // 1 MB
  unsigned short* kpl = (unsigned short*)(base + 19922944);       // 1 MB
  unsigned short* vp  = (unsigned short*)(base + 20971520);       // 1 MB
  // region [22020096, ...): wh/wl during qkv, then pden/pM during attn/merge
  unsigned short* wh  = (unsigned short*)(base + 22020096);       // 192 KB
  unsigned short* wl  = (unsigned short*)(base + 22216704);       // 192 KB
  float* pden = (float*)(base + 22020096);                        // 256 KB (aliases wh/wl)
  float* pM   = (float*)(base + 22282240);                        // 256 KB
  float* pnum = (float*)(base);                                   // 16 MB (aliases xh/xl)

  split_x<<<(N_TOK * D_INN) / (256 * 8), 256, 0, stream>>>(X, (unsigned*)xh, (unsigned*)xl);
  prep_w<<<384, 256, 0, stream>>>(Wq, Wk, Wv, wh, wl);
  qkv2<<<N_TOK / 16, 256, 0, stream>>>(xh, xl, wh, wl, qhp, qlp, kph, kpl, vp);
  attn3<<<512, 256, 0, stream>>>(qhp, qlp, kph, kpl, vp, pnum, pden, pM);
  merge8<<<(N_TOK * DK) / 256, 256, 0, stream>>>(pnum, pden, pM, (float*)d_out);
}